// Round 13
// baseline (240.492 us; speedup 1.0000x reference)
//
#include <hip/hip_runtime.h>

#define L_SEQ   4096
#define D_MODEL 512
#define NSEQ    2048   // BATCH * D_MODEL
#define CH      128    // chunk length
#define NC      32     // chunks

// workspace float offsets
#define OFF_P    0        // P = A^128, [i][j] row-major, 4096
#define OFF_W1T  4096     // W1T[r][i] = (A^{127-r} b)[i], 128x64
#define OFF_WOUT 12288    // Wout[i][r] = (c^T A^{r+1})[i], 64x128
#define OFF_KLOC 20480    // KlocZ[0..127]=0, KlocZ[128+m]=c^T A^m b, 256
#define OFF_KZ3  20736    // Kz3[m] = KlocZ[m-3], 264 floats (tail zero-padded)
#define OFF_GX   21760    // gx[c][s][i]: proj writes G, scan overwrites X_c

#define BC(v, j) __int_as_float(__builtin_amdgcn_readlane(__float_as_int(v), (j)))

// ===========================================================================
// k_prep (1 block, 1024 threads = 16 waves): power ladder S=A^{2^t} via 7
// squarings; vr/cw tables by log-doubling GEMMs. (unchanged)
// ===========================================================================
__global__ __launch_bounds__(1024) void k_prep(
    const float* __restrict__ A, const float* __restrict__ B,
    const float* __restrict__ C, float* __restrict__ ws) {
  __shared__ float Srow[64][68];   // S[i][k]
  __shared__ float STs[64][68];    // STs[k][i] = S[i][k]
  __shared__ float vrT[128][68];   // vrT[m][i] = (A^m b)[i]
  __shared__ float cwS[129][68];   // cwS[m][j] = (c^T A^m)[j], m=1..128
  __shared__ float Cs[64], Bsh[64];
  __shared__ float KzSh[256];

  const int tid = threadIdx.x;
  if (tid < 64) { Cs[tid] = C[tid]; Bsh[tid] = B[tid]; }
  for (int e = tid; e < 4096; e += 1024) {
    const float a = A[e];
    Srow[e >> 6][e & 63] = a;
    STs[e & 63][e >> 6] = a;
  }
  __syncthreads();

  // seeds: vr[0] = b ; cw[1] = c^T A
  if (tid < 64) {
    vrT[0][tid] = Bsh[tid];
    float acc = 0.f;
#pragma unroll
    for (int k = 0; k < 64; ++k) acc += Cs[k] * STs[tid][k];  // A[k][tid]
    cwS[1][tid] = acc;
  }
  __syncthreads();

  const bool sq = (tid >= 768);            // squaring wave group (4 waves)
  const int stid = tid & 255;
  const int iy4 = (stid >> 4) * 4, jx4 = (stid & 15) * 4;

  for (int t = 0; t < 7; ++t) {
    const int nd = 1 << t;

    // ---- extensions using S = A^nd (threads 0..511 max; 1 tile/thread)
    if (nd <= 2) {
      const int total = 2 * nd * 64;
      if (tid < total) {
        const int half = (tid >= nd * 64);
        const int o = (tid >> 6) & (nd - 1);
        const int idx = tid & 63;
        float acc = 0.f;
        if (!half) {
#pragma unroll
          for (int k = 0; k < 64; ++k) acc += vrT[o][k] * Srow[idx][k];
          vrT[nd + o][idx] = acc;            // (A^nd vr[o])[idx]
        } else {
#pragma unroll
          for (int k = 0; k < 64; ++k) acc += cwS[1 + o][k] * STs[idx][k];
          cwS[nd + 1 + o][idx] = acc;        // (cw[1+o] A^nd)[idx]
        }
      }
    } else {
      const int tpg = nd * 4;              // tiles per GEMM; 2*tpg <= 512
      if (tid < 2 * tpg) {
        const int half = (tid >= tpg);
        const int q = half ? tid - tpg : tid;
        const int m0 = (q >> 4) * 4;
        const int i0 = (q & 15) * 4;
        float acc[4][4] = {{0.f}};
        if (!half) {
          // vrT[nd+m][i] = sum_k vrT[m][k] * S[i][k]
#pragma unroll 4
          for (int k = 0; k < 64; k += 4) {
            float a_[4][4];
#pragma unroll
            for (int r = 0; r < 4; ++r)
              *(float4*)&a_[r][0] = *(const float4*)&vrT[m0 + r][k];
#pragma unroll
            for (int kk = 0; kk < 4; ++kk) {
              const float4 b4 = *(const float4*)&STs[k + kk][i0];
#pragma unroll
              for (int r = 0; r < 4; ++r) {
                const float av = a_[r][kk];
                acc[r][0] += av * b4.x; acc[r][1] += av * b4.y;
                acc[r][2] += av * b4.z; acc[r][3] += av * b4.w;
              }
            }
          }
#pragma unroll
          for (int r = 0; r < 4; ++r) {
            float4 v; v.x = acc[r][0]; v.y = acc[r][1]; v.z = acc[r][2]; v.w = acc[r][3];
            *(float4*)&vrT[nd + m0 + r][i0] = v;
          }
        } else {
          // cwS[nd+1+m][j] = sum_k cwS[1+m][k] * S[k][j]
#pragma unroll 4
          for (int k = 0; k < 64; k += 4) {
            float a_[4][4];
#pragma unroll
            for (int r = 0; r < 4; ++r)
              *(float4*)&a_[r][0] = *(const float4*)&cwS[1 + m0 + r][k];
#pragma unroll
            for (int kk = 0; kk < 4; ++kk) {
              const float4 b4 = *(const float4*)&Srow[k + kk][i0];
#pragma unroll
              for (int r = 0; r < 4; ++r) {
                const float av = a_[r][kk];
                acc[r][0] += av * b4.x; acc[r][1] += av * b4.y;
                acc[r][2] += av * b4.z; acc[r][3] += av * b4.w;
              }
            }
          }
#pragma unroll
          for (int r = 0; r < 4; ++r) {
            float4 v; v.x = acc[r][0]; v.y = acc[r][1]; v.z = acc[r][2]; v.w = acc[r][3];
            *(float4*)&cwS[nd + 1 + m0 + r][i0] = v;
          }
        }
      }
    }

    // ---- squaring S -> S^2 in regs (threads 768..1023; reads Srow only)
    float sacc[4][4] = {{0.f}};
    if (sq) {
#pragma unroll 4
      for (int k = 0; k < 64; k += 4) {
        float a_[4][4];
#pragma unroll
        for (int r = 0; r < 4; ++r)
          *(float4*)&a_[r][0] = *(const float4*)&Srow[iy4 + r][k];
#pragma unroll
        for (int kk = 0; kk < 4; ++kk) {
          const float4 b4 = *(const float4*)&Srow[k + kk][jx4];
#pragma unroll
          for (int r = 0; r < 4; ++r) {
            const float av = a_[r][kk];
            sacc[r][0] += av * b4.x; sacc[r][1] += av * b4.y;
            sacc[r][2] += av * b4.z; sacc[r][3] += av * b4.w;
          }
        }
      }
    }
    __syncthreads();   // all reads of S done (ext + squaring)
    if (sq) {
#pragma unroll
      for (int r = 0; r < 4; ++r) {
        float4 v; v.x = sacc[r][0]; v.y = sacc[r][1]; v.z = sacc[r][2]; v.w = sacc[r][3];
        *(float4*)&Srow[iy4 + r][jx4] = v;
      }
#pragma unroll
      for (int c = 0; c < 4; ++c) {
        float4 v; v.x = sacc[0][c]; v.y = sacc[1][c]; v.z = sacc[2][c]; v.w = sacc[3][c];
        *(float4*)&STs[jx4 + c][iy4] = v;
      }
    }
    __syncthreads();
  }
  // now: Srow = A^128, vrT rows 0..127, cwS rows 1..128

  // P
  float* Pg = ws + OFF_P;
  for (int e = tid; e < 4096; e += 1024) Pg[e] = Srow[e >> 6][e & 63];

  // W1T[r][i] = vr[127-r][i]
  float* W1Tg = ws + OFF_W1T;
  for (int e = tid; e < 8192; e += 1024) W1Tg[e] = vrT[127 - (e >> 6)][e & 63];

  // Wout[i][r] = cw[r+1][i]
  float* Wg = ws + OFF_WOUT;
  for (int e = tid; e < 8192; e += 1024) Wg[e] = cwS[(e & 127) + 1][e >> 7];

  // Kloc: KzSh[128+m] = sum_i C[i]*vr[m][i]; zeros in front as guard
  float* Kz = ws + OFF_KLOC;
  if (tid < 128) {
    float acc = 0.f;
#pragma unroll
    for (int i = 0; i < 64; ++i) acc += Cs[i] * vrT[tid][i];
    KzSh[128 + tid] = acc;
    Kz[128 + tid] = acc;
  } else if (tid < 256) {
    KzSh[tid - 128] = 0.f;
    Kz[tid - 128] = 0.f;
  }
  __syncthreads();

  // Kz3[m] = KzSh[m - 3], zero-padded tail (window reads touch up to m=259)
  float* Kz3g = ws + OFF_KZ3;
  if (tid < 264) Kz3g[tid] = (tid >= 3 && tid < 259) ? KzSh[tid - 3] : 0.f;
}

// ===========================================================================
// k_proj REWRITE: broadcast matvec. lane = s (coalesced u dword per r),
// wave = one 16-i group; W1T row chunk = 4 wave-broadcast float4 from
// global (L1-hot 32KB shared panel). No LDS, no barriers, 16 acc regs.
// Per r: 5 loads + 16 FMA. Grid 32sg x 32c, 256 thr -> 16 waves/CU at
// ~32 VGPR. Old GEMM-style proj measured 42.6us @ VALUBusy 17.5% (L1-BW/
// latency bound on W1T movement); this removes the movement entirely.
// FMA order per g[s][i]: r ascending 0..127 -> bit-identical.
// ===========================================================================
__global__ __launch_bounds__(256) void k_proj(
    const float* __restrict__ u, const float* __restrict__ wsr,
    float* __restrict__ gx) {
  const int sg = blockIdx.x;   // 0..31: 64-seq group
  const int c  = blockIdx.y;   // 0..31: chunk
  const int tid = threadIdx.x;
  const int lane = tid & 63, w = tid >> 6;
  const int i0 = w * 16;
  const int s = sg * 64 + lane;          // global seq (wave spans one bi)
  const int bi = s >> 9, d = s & 511;

  const float* W1Tg = wsr + OFF_W1T;     // [r][i]
  const float* up = u + ((size_t)bi * L_SEQ + c * CH) * D_MODEL + d;

  float acc[16];
#pragma unroll
  for (int j = 0; j < 16; ++j) acc[j] = 0.f;

#pragma unroll 4
  for (int r = 0; r < 128; ++r) {
    const float uv = up[(size_t)r * D_MODEL];
    const float4 b0 = *(const float4*)(W1Tg + r * 64 + i0);
    const float4 b1 = *(const float4*)(W1Tg + r * 64 + i0 + 4);
    const float4 b2 = *(const float4*)(W1Tg + r * 64 + i0 + 8);
    const float4 b3 = *(const float4*)(W1Tg + r * 64 + i0 + 12);
    acc[0]  += uv * b0.x; acc[1]  += uv * b0.y;
    acc[2]  += uv * b0.z; acc[3]  += uv * b0.w;
    acc[4]  += uv * b1.x; acc[5]  += uv * b1.y;
    acc[6]  += uv * b1.z; acc[7]  += uv * b1.w;
    acc[8]  += uv * b2.x; acc[9]  += uv * b2.y;
    acc[10] += uv * b2.z; acc[11] += uv * b2.w;
    acc[12] += uv * b3.x; acc[13] += uv * b3.y;
    acc[14] += uv * b3.z; acc[15] += uv * b3.w;
  }

  // write gx[c][s][i0..i0+15] (contiguous 64B per thread)
  float* gb = gx + ((size_t)c * NSEQ + s) * 64 + i0;
#pragma unroll
  for (int j4 = 0; j4 < 4; ++j4) {
    float4 v;
    v.x = acc[j4 * 4 + 0]; v.y = acc[j4 * 4 + 1];
    v.z = acc[j4 * 4 + 2]; v.w = acc[j4 * 4 + 3];
    *(float4*)(gb + j4 * 4) = v;
  }
}

// ===========================================================================
// k_scan: x_{c+1} = P x_c + g_c. One seq per wave, lane = state.
// 4-deep chunk prefetch pipeline. (unchanged)
// ===========================================================================
__global__ __launch_bounds__(256) void k_scan(
    const float* __restrict__ wsr, float* __restrict__ gx) {
  const int lane = threadIdx.x & 63, wv = threadIdx.x >> 6;
  const int s = blockIdx.x * 4 + wv;

  float p[64];
  {
    const float* pr = wsr + OFF_P + lane * 64;
#pragma unroll
    for (int j = 0; j < 64; j += 4) {
      const float4 v = *(const float4*)(pr + j);
      p[j] = v.x; p[j + 1] = v.y; p[j + 2] = v.z; p[j + 3] = v.w;
    }
  }

  const size_t CS = (size_t)NSEQ * 64;
  float* gs = gx + (size_t)s * 64 + lane;
  float x = 0.f;
  float g0 = gs[0];
  float g1 = gs[CS];
  float g2 = gs[2 * CS];
  float g3 = gs[3 * CS];
  for (int c = 0; c < NC; ++c) {
    const float gn = (c + 4 < NC) ? gs[(size_t)(c + 4) * CS] : 0.f;
    gs[(size_t)c * CS] = x;  // overwrite g[c] with pre-chunk state X_c
    float x0 = g0, x1 = 0.f;
#pragma unroll
    for (int j = 0; j < 64; j += 2) {
      x0 += p[j] * BC(x, j);
      x1 += p[j + 1] * BC(x, j + 1);
    }
    x = x0 + x1;
    g0 = g1; g1 = g2; g2 = g3; g3 = gn;
  }
}

// ===========================================================================
// k_localout: REVERTED to the round-9 best (43.4us measured; rounds 10-12
// alternatives all equal or worse). 128r x 64s per block, 256 threads, 8x4
// micro. Phase A: Toeplitz sliding window on Kz3 (4 bank-staggered LDS
// copies, stride 276 -> bank offsets {0,20,8,28}). Phase B: Wout i-half
// LDS panels (16KB x2) + X transpose. LDS 37.2KB -> 4 blocks/CU.
// ===========================================================================
#define LB(k, s)   LDSf[(k) * 64 + (s)]
#define LKZ3       4096           // 4 copies x 276 floats
#define LAW(i, r)  LDSf[5200 + (i) * 128 + (r)]

__global__ __launch_bounds__(256) void k_localout(
    const float* __restrict__ u, const float* __restrict__ wsr,
    const float* __restrict__ gx, float* __restrict__ out) {
  __shared__ float LDSf[9296];   // 37184 B

  const int sg = blockIdx.x;      // 0..31 (64 seqs each)
  const int c = blockIdx.y;       // 0..31 (chunk)
  const int sgl = sg * 64;
  const int bi = sgl >> 9, d0 = sgl & 511;

  const float* Kz3g = wsr + OFF_KZ3;
  const float* WoutG = wsr + OFF_WOUT;
  const float* ub = u + ((size_t)bi * L_SEQ + c * CH) * D_MODEL + d0;

  const int tid = threadIdx.x;
  const int ry8 = (tid >> 4) * 8;   // 8 rows (wave w owns rows w*32..w*32+31)
  const int sx4 = (tid & 15) * 4;   // 4 s-cols

  // stage Kz3 x4 copies (threads 0..65, one float4 each, replicated)
  if (tid < 66) {
    const float4 v = *(const float4*)(Kz3g + tid * 4);
#pragma unroll
    for (int q = 0; q < 4; ++q)
      *(float4*)&LDSf[LKZ3 + q * 276 + tid * 4] = v;
  }

  float acc[8][4];
#pragma unroll
  for (int r = 0; r < 8; ++r)
#pragma unroll
    for (int cc = 0; cc < 4; ++cc) acc[r][cc] = 0.f;

  const float* lkz = &LDSf[LKZ3 + ((tid >> 4) & 3) * 276];

  // phase A: within-chunk Toeplitz, K = 128 in two 64-k stages
  for (int kt = 0; kt < 2; ++kt) {
    const int k0 = kt * 64;
#pragma unroll
    for (int e4 = 0; e4 < 4; ++e4) {
      const int e = tid + 256 * e4;          // 1024 float4 over 64x64 u tile
      const int kk = e >> 4, s4 = (e & 15) * 4;
      *(float4*)&LB(kk, s4) =
          *(const float4*)(ub + (size_t)(k0 + kk) * D_MODEL + s4);
    }
    __syncthreads();
    const int base = 128 - k0;
    // kt=1: rows <64 have zero contribution (guard zone); wave-uniform skip.
    if (kt == 0 || ry8 >= 64) {
#pragma unroll 4
      for (int g = 0; g < 16; ++g) {
        const int Wg = base + ry8 - 4 * g;     // mult of 4 -> aligned reads
        const float4 w0 = *(const float4*)&lkz[Wg];
        const float4 w1 = *(const float4*)&lkz[Wg + 4];
        const float4 w2 = *(const float4*)&lkz[Wg + 8];
        const float w[12] = {w0.x, w0.y, w0.z, w0.w, w1.x, w1.y, w1.z, w1.w,
                             w2.x, w2.y, w2.z, w2.w};
#pragma unroll
        for (int k2 = 0; k2 < 4; ++k2) {
          const float4 b = *(const float4*)&LB(4 * g + k2, sx4);
          const float bv[4] = {b.x, b.y, b.z, b.w};
#pragma unroll
          for (int ii = 0; ii < 8; ++ii) {
            const float av = w[ii - k2 + 3];   // = KlocZ[base+ry8+ii-(4g+k2)]
#pragma unroll
            for (int jj = 0; jj < 4; ++jj) acc[ii][jj] += av * bv[jj];
          }
        }
      }
    }
    __syncthreads();
  }

  // phase B: Wout * X_c, i split into two 32-i halves (16KB AW panel each)
  const float* xc = gx + ((size_t)c * NSEQ + sgl) * 64;
  for (int ih = 0; ih < 2; ++ih) {
    // AW[i][r] = Wout[ih*32+i][r], 32x128 (1024 float4, 4/thread)
#pragma unroll
    for (int e4 = 0; e4 < 4; ++e4) {
      const int e = tid + 256 * e4;
      const int i_ = e >> 5, r4 = (e & 31) * 4;
      *(float4*)&LAW(i_, r4) =
          *(const float4*)(WoutG + (ih * 32 + i_) * 128 + r4);
    }
    // Bs = X half [32i][64s] from gx[c][s][i] (512 float4, 2/thread);
    // sl-major scalar scatter writes (banks = sl%32, 2-way = free).
#pragma unroll
    for (int e2 = 0; e2 < 2; ++e2) {
      const int e = tid + 256 * e2;
      const int sl = e & 63, i4 = ((e >> 6) & 7) * 4;
      const float4 v = *(const float4*)(xc + (size_t)sl * 64 + ih * 32 + i4);
      LB(i4 + 0, sl) = v.x;
      LB(i4 + 1, sl) = v.y;
      LB(i4 + 2, sl) = v.z;
      LB(i4 + 3, sl) = v.w;
    }
    __syncthreads();
#pragma unroll 8
    for (int kk = 0; kk < 32; ++kk) {
      const float4 a0 = *(const float4*)&LAW(kk, ry8);
      const float4 a1 = *(const float4*)&LAW(kk, ry8 + 4);
      const float4 b = *(const float4*)&LB(kk, sx4);
      const float av[8] = {a0.x, a0.y, a0.z, a0.w, a1.x, a1.y, a1.z, a1.w};
      const float bv[4] = {b.x, b.y, b.z, b.w};
#pragma unroll
      for (int ii = 0; ii < 8; ++ii)
#pragma unroll
        for (int jj = 0; jj < 4; ++jj) acc[ii][jj] += av[ii] * bv[jj];
    }
    __syncthreads();
  }

  // epilogue: rows ry8..ry8+7, cols sx4..sx4+3
  float* ob = out + ((size_t)bi * L_SEQ + c * CH) * D_MODEL + d0;
#pragma unroll
  for (int r = 0; r < 8; ++r) {
    float4 v; v.x = acc[r][0]; v.y = acc[r][1]; v.z = acc[r][2]; v.w = acc[r][3];
    *(float4*)(ob + (size_t)(ry8 + r) * D_MODEL + sx4) = v;
  }
}

extern "C" void kernel_launch(void* const* d_in, const int* in_sizes, int n_in,
                              void* d_out, int out_size, void* d_ws,
                              size_t ws_size, hipStream_t stream) {
  const float* u = (const float*)d_in[0];   // (4, 4096, 512)
  const float* A = (const float*)d_in[1];   // (64, 64)
  const float* B = (const float*)d_in[2];   // (64, 1)
  const float* C = (const float*)d_in[3];   // (1, 64)
  float* out = (float*)d_out;
  float* ws = (float*)d_ws;                 // needs ~16.9 MB
  float* gx = ws + OFF_GX;

  k_prep<<<1, 1024, 0, stream>>>(A, B, C, ws);
  k_proj<<<dim3(32, 32), 256, 0, stream>>>(u, ws, gx);
  k_scan<<<512, 256, 0, stream>>>(ws, gx);
  k_localout<<<dim3(32, 32), 256, 0, stream>>>(u, ws, gx, out);
}

// Round 15
// 189.199 us; speedup vs baseline: 1.2711x; 1.2711x over previous
//
#include <hip/hip_runtime.h>

#define L_SEQ   4096
#define D_MODEL 512
#define NSEQ    2048   // BATCH * D_MODEL
#define CH      128    // chunk length
#define NC      32     // chunks

// workspace float offsets
#define OFF_P    0        // P = A^128, [i][j] row-major, 4096
#define OFF_W1T  4096     // W1T[r][i] = (A^{127-r} b)[i], 128x64
#define OFF_WOUT 12288    // Wout[i][r] = (c^T A^{r+1})[i], 64x128
#define OFF_KLOC 20480    // KlocZ[0..127]=0, KlocZ[128+m]=c^T A^m b, 256
#define OFF_KZ3  20736    // Kz3[m] = KlocZ[m-3], 264 floats (tail zero-padded)
#define OFF_GX   21760    // gx[c][s][i]: proj writes G, scan overwrites X_c

#define BC(v, j) __int_as_float(__builtin_amdgcn_readlane(__float_as_int(v), (j)))

// ===========================================================================
// k_prep (1 block, 1024 threads = 16 waves): power ladder S=A^{2^t} via 7
// squarings; vr/cw tables by log-doubling GEMMs. (unchanged)
// ===========================================================================
__global__ __launch_bounds__(1024) void k_prep(
    const float* __restrict__ A, const float* __restrict__ B,
    const float* __restrict__ C, float* __restrict__ ws) {
  __shared__ float Srow[64][68];   // S[i][k]
  __shared__ float STs[64][68];    // STs[k][i] = S[i][k]
  __shared__ float vrT[128][68];   // vrT[m][i] = (A^m b)[i]
  __shared__ float cwS[129][68];   // cwS[m][j] = (c^T A^m)[j], m=1..128
  __shared__ float Cs[64], Bsh[64];
  __shared__ float KzSh[256];

  const int tid = threadIdx.x;
  if (tid < 64) { Cs[tid] = C[tid]; Bsh[tid] = B[tid]; }
  for (int e = tid; e < 4096; e += 1024) {
    const float a = A[e];
    Srow[e >> 6][e & 63] = a;
    STs[e & 63][e >> 6] = a;
  }
  __syncthreads();

  // seeds: vr[0] = b ; cw[1] = c^T A
  if (tid < 64) {
    vrT[0][tid] = Bsh[tid];
    float acc = 0.f;
#pragma unroll
    for (int k = 0; k < 64; ++k) acc += Cs[k] * STs[tid][k];  // A[k][tid]
    cwS[1][tid] = acc;
  }
  __syncthreads();

  const bool sq = (tid >= 768);            // squaring wave group (4 waves)
  const int stid = tid & 255;
  const int iy4 = (stid >> 4) * 4, jx4 = (stid & 15) * 4;

  for (int t = 0; t < 7; ++t) {
    const int nd = 1 << t;

    // ---- extensions using S = A^nd (threads 0..511 max; 1 tile/thread)
    if (nd <= 2) {
      const int total = 2 * nd * 64;
      if (tid < total) {
        const int half = (tid >= nd * 64);
        const int o = (tid >> 6) & (nd - 1);
        const int idx = tid & 63;
        float acc = 0.f;
        if (!half) {
#pragma unroll
          for (int k = 0; k < 64; ++k) acc += vrT[o][k] * Srow[idx][k];
          vrT[nd + o][idx] = acc;            // (A^nd vr[o])[idx]
        } else {
#pragma unroll
          for (int k = 0; k < 64; ++k) acc += cwS[1 + o][k] * STs[idx][k];
          cwS[nd + 1 + o][idx] = acc;        // (cw[1+o] A^nd)[idx]
        }
      }
    } else {
      const int tpg = nd * 4;              // tiles per GEMM; 2*tpg <= 512
      if (tid < 2 * tpg) {
        const int half = (tid >= tpg);
        const int q = half ? tid - tpg : tid;
        const int m0 = (q >> 4) * 4;
        const int i0 = (q & 15) * 4;
        float acc[4][4] = {{0.f}};
        if (!half) {
          // vrT[nd+m][i] = sum_k vrT[m][k] * S[i][k]
#pragma unroll 4
          for (int k = 0; k < 64; k += 4) {
            float a_[4][4];
#pragma unroll
            for (int r = 0; r < 4; ++r)
              *(float4*)&a_[r][0] = *(const float4*)&vrT[m0 + r][k];
#pragma unroll
            for (int kk = 0; kk < 4; ++kk) {
              const float4 b4 = *(const float4*)&STs[k + kk][i0];
#pragma unroll
              for (int r = 0; r < 4; ++r) {
                const float av = a_[r][kk];
                acc[r][0] += av * b4.x; acc[r][1] += av * b4.y;
                acc[r][2] += av * b4.z; acc[r][3] += av * b4.w;
              }
            }
          }
#pragma unroll
          for (int r = 0; r < 4; ++r) {
            float4 v; v.x = acc[r][0]; v.y = acc[r][1]; v.z = acc[r][2]; v.w = acc[r][3];
            *(float4*)&vrT[nd + m0 + r][i0] = v;
          }
        } else {
          // cwS[nd+1+m][j] = sum_k cwS[1+m][k] * S[k][j]
#pragma unroll 4
          for (int k = 0; k < 64; k += 4) {
            float a_[4][4];
#pragma unroll
            for (int r = 0; r < 4; ++r)
              *(float4*)&a_[r][0] = *(const float4*)&cwS[1 + m0 + r][k];
#pragma unroll
            for (int kk = 0; kk < 4; ++kk) {
              const float4 b4 = *(const float4*)&Srow[k + kk][i0];
#pragma unroll
              for (int r = 0; r < 4; ++r) {
                const float av = a_[r][kk];
                acc[r][0] += av * b4.x; acc[r][1] += av * b4.y;
                acc[r][2] += av * b4.z; acc[r][3] += av * b4.w;
              }
            }
          }
#pragma unroll
          for (int r = 0; r < 4; ++r) {
            float4 v; v.x = acc[r][0]; v.y = acc[r][1]; v.z = acc[r][2]; v.w = acc[r][3];
            *(float4*)&cwS[nd + 1 + m0 + r][i0] = v;
          }
        }
      }
    }

    // ---- squaring S -> S^2 in regs (threads 768..1023; reads Srow only)
    float sacc[4][4] = {{0.f}};
    if (sq) {
#pragma unroll 4
      for (int k = 0; k < 64; k += 4) {
        float a_[4][4];
#pragma unroll
        for (int r = 0; r < 4; ++r)
          *(float4*)&a_[r][0] = *(const float4*)&Srow[iy4 + r][k];
#pragma unroll
        for (int kk = 0; kk < 4; ++kk) {
          const float4 b4 = *(const float4*)&Srow[k + kk][jx4];
#pragma unroll
          for (int r = 0; r < 4; ++r) {
            const float av = a_[r][kk];
            sacc[r][0] += av * b4.x; sacc[r][1] += av * b4.y;
            sacc[r][2] += av * b4.z; sacc[r][3] += av * b4.w;
          }
        }
      }
    }
    __syncthreads();   // all reads of S done (ext + squaring)
    if (sq) {
#pragma unroll
      for (int r = 0; r < 4; ++r) {
        float4 v; v.x = sacc[r][0]; v.y = sacc[r][1]; v.z = sacc[r][2]; v.w = sacc[r][3];
        *(float4*)&Srow[iy4 + r][jx4] = v;
      }
#pragma unroll
      for (int c = 0; c < 4; ++c) {
        float4 v; v.x = sacc[0][c]; v.y = sacc[1][c]; v.z = sacc[2][c]; v.w = sacc[3][c];
        *(float4*)&STs[jx4 + c][iy4] = v;
      }
    }
    __syncthreads();
  }
  // now: Srow = A^128, vrT rows 0..127, cwS rows 1..128

  // P
  float* Pg = ws + OFF_P;
  for (int e = tid; e < 4096; e += 1024) Pg[e] = Srow[e >> 6][e & 63];

  // W1T[r][i] = vr[127-r][i]
  float* W1Tg = ws + OFF_W1T;
  for (int e = tid; e < 8192; e += 1024) W1Tg[e] = vrT[127 - (e >> 6)][e & 63];

  // Wout[i][r] = cw[r+1][i]
  float* Wg = ws + OFF_WOUT;
  for (int e = tid; e < 8192; e += 1024) Wg[e] = cwS[(e & 127) + 1][e >> 7];

  // Kloc: KzSh[128+m] = sum_i C[i]*vr[m][i]; zeros in front as guard
  float* Kz = ws + OFF_KLOC;
  if (tid < 128) {
    float acc = 0.f;
#pragma unroll
    for (int i = 0; i < 64; ++i) acc += Cs[i] * vrT[tid][i];
    KzSh[128 + tid] = acc;
    Kz[128 + tid] = acc;
  } else if (tid < 256) {
    KzSh[tid - 128] = 0.f;
    Kz[tid - 128] = 0.f;
  }
  __syncthreads();

  // Kz3[m] = KzSh[m - 3], zero-padded tail (window reads touch up to m=259)
  float* Kz3g = ws + OFF_KZ3;
  if (tid < 264) Kz3g[tid] = (tid >= 3 && tid < 259) ? KzSh[tid - 3] : 0.f;
}

// ===========================================================================
// k_proj: round-8 LDS-staged version (part of the 189.7us best config;
// global-direct W1T variants measured 42.6us @ VALUBusy 17.5% and 86us @
// 9.7% -- vmem-issue/L1-BW bound. Small shared panels must be LDS-staged).
// 64s x 64i tile, 256 threads, 4x4 micro, W1 staged per 64-K half
// ([64][64] = 16KB) -> LDS 32KB -> 4 blocks/CU = 16 waves/CU.
// ===========================================================================
__global__ __launch_bounds__(256) void k_proj(
    const float* __restrict__ u, const float* __restrict__ wsr,
    float* __restrict__ gx) {
  __shared__ float W1h[64][64];
  __shared__ float Us[64][64];

  const int st = blockIdx.x;   // 0..31 (64 seqs each)
  const int c = blockIdx.y;    // 0..31
  const int tid = threadIdx.x;
  const int sgl = st * 64;
  const int bi = sgl >> 9, d0 = sgl & 511;

  const float* W1Tg = wsr + OFF_W1T;
  const float* ub = u + ((size_t)bi * L_SEQ + c * CH) * D_MODEL + d0;
  const int sy4 = (tid >> 4) * 4;   // s group (0..15)*4
  const int ix4 = (tid & 15) * 4;   // i group (0..15)*4

  float acc[4][4];
#pragma unroll
  for (int r = 0; r < 4; ++r)
#pragma unroll
    for (int cc = 0; cc < 4; ++cc) acc[r][cc] = 0.f;

  for (int h = 0; h < 2; ++h) {
    __syncthreads();
#pragma unroll
    for (int e4 = 0; e4 < 4; ++e4) {
      const int e = tid + 256 * e4;       // 1024 float4 over 64x64 u tile
      const int rr = e >> 4, s4 = (e & 15) * 4;
      *(float4*)&Us[rr][s4] =
          *(const float4*)(ub + (size_t)(h * 64 + rr) * D_MODEL + s4);
    }
#pragma unroll
    for (int e4 = 0; e4 < 4; ++e4) {
      const int e = tid + 256 * e4;       // 1024 float4 over 64x64 W1 half
      *(float4*)&W1h[e >> 4][(e & 15) * 4] =
          *(const float4*)(W1Tg + (size_t)(h * 1024 + e) * 4);
    }
    __syncthreads();
#pragma unroll 8
    for (int kk = 0; kk < 64; ++kk) {
      const float4 a = *(const float4*)&Us[kk][sy4];
      const float4 b = *(const float4*)&W1h[kk][ix4];
      const float av[4] = {a.x, a.y, a.z, a.w};
      const float bv[4] = {b.x, b.y, b.z, b.w};
#pragma unroll
      for (int ii = 0; ii < 4; ++ii)
#pragma unroll
        for (int jj = 0; jj < 4; ++jj) acc[ii][jj] += av[ii] * bv[jj];
    }
  }

  // write gx[c][s][i] (i contiguous)
  float* gb = gx + ((size_t)c * NSEQ + sgl) * 64;
#pragma unroll
  for (int j = 0; j < 4; ++j) {
    float4 v; v.x = acc[j][0]; v.y = acc[j][1]; v.z = acc[j][2]; v.w = acc[j][3];
    *(float4*)(gb + (size_t)(sy4 + j) * 64 + ix4) = v;
  }
}

// ===========================================================================
// k_scan: x_{c+1} = P x_c + g_c. One seq per wave, lane = state.
// 8-deep chunk prefetch (was 4). Little's law: 2048 waves x 4 x 256B = 2MB
// in flight -> ~2.2 TB/s effective at ~900ns HBM latency; depth 8 -> 4.2MB
// ~= latency-BW product. Named registers g0..g7 (no runtime-indexed array).
// Store of chunk c happens >=8 iters after its read -> in-place safe.
// ===========================================================================
__global__ __launch_bounds__(256) void k_scan(
    const float* __restrict__ wsr, float* __restrict__ gx) {
  const int lane = threadIdx.x & 63, wv = threadIdx.x >> 6;
  const int s = blockIdx.x * 4 + wv;

  float p[64];
  {
    const float* pr = wsr + OFF_P + lane * 64;
#pragma unroll
    for (int j = 0; j < 64; j += 4) {
      const float4 v = *(const float4*)(pr + j);
      p[j] = v.x; p[j + 1] = v.y; p[j + 2] = v.z; p[j + 3] = v.w;
    }
  }

  const size_t CS = (size_t)NSEQ * 64;
  float* gs = gx + (size_t)s * 64 + lane;
  float x = 0.f;
  float g0 = gs[0];
  float g1 = gs[CS];
  float g2 = gs[2 * CS];
  float g3 = gs[3 * CS];
  float g4 = gs[4 * CS];
  float g5 = gs[5 * CS];
  float g6 = gs[6 * CS];
  float g7 = gs[7 * CS];
  for (int c = 0; c < NC; ++c) {
    const float gn = (c + 8 < NC) ? gs[(size_t)(c + 8) * CS] : 0.f;
    gs[(size_t)c * CS] = x;  // overwrite g[c] with pre-chunk state X_c
    float x0 = g0, x1 = 0.f;
#pragma unroll
    for (int j = 0; j < 64; j += 2) {
      x0 += p[j] * BC(x, j);
      x1 += p[j + 1] * BC(x, j + 1);
    }
    x = x0 + x1;
    g0 = g1; g1 = g2; g2 = g3; g3 = g4;
    g4 = g5; g5 = g6; g6 = g7; g7 = gn;
  }
}

// ===========================================================================
// k_localout: round-8 best (43.4us measured; r10-12 alternatives all worse).
// 128r x 64s per block, 256 threads, 8x4 micro. Phase A: Toeplitz sliding
// window on Kz3 (4 bank-staggered LDS copies, stride 276 -> bank offsets
// {0,20,8,28}). Phase B: Wout i-half LDS panels (16KB x2) + X transpose.
// LDS 37.2KB -> 4 blocks/CU. (unchanged)
// ===========================================================================
#define LB(k, s)   LDSf[(k) * 64 + (s)]
#define LKZ3       4096           // 4 copies x 276 floats
#define LAW(i, r)  LDSf[5200 + (i) * 128 + (r)]

__global__ __launch_bounds__(256) void k_localout(
    const float* __restrict__ u, const float* __restrict__ wsr,
    const float* __restrict__ gx, float* __restrict__ out) {
  __shared__ float LDSf[9296];   // 37184 B

  const int sg = blockIdx.x;      // 0..31 (64 seqs each)
  const int c = blockIdx.y;       // 0..31 (chunk)
  const int sgl = sg * 64;
  const int bi = sgl >> 9, d0 = sgl & 511;

  const float* Kz3g = wsr + OFF_KZ3;
  const float* WoutG = wsr + OFF_WOUT;
  const float* ub = u + ((size_t)bi * L_SEQ + c * CH) * D_MODEL + d0;

  const int tid = threadIdx.x;
  const int ry8 = (tid >> 4) * 8;   // 8 rows (wave w owns rows w*32..w*32+31)
  const int sx4 = (tid & 15) * 4;   // 4 s-cols

  // stage Kz3 x4 copies (threads 0..65, one float4 each, replicated)
  if (tid < 66) {
    const float4 v = *(const float4*)(Kz3g + tid * 4);
#pragma unroll
    for (int q = 0; q < 4; ++q)
      *(float4*)&LDSf[LKZ3 + q * 276 + tid * 4] = v;
  }

  float acc[8][4];
#pragma unroll
  for (int r = 0; r < 8; ++r)
#pragma unroll
    for (int cc = 0; cc < 4; ++cc) acc[r][cc] = 0.f;

  const float* lkz = &LDSf[LKZ3 + ((tid >> 4) & 3) * 276];

  // phase A: within-chunk Toeplitz, K = 128 in two 64-k stages
  for (int kt = 0; kt < 2; ++kt) {
    const int k0 = kt * 64;
#pragma unroll
    for (int e4 = 0; e4 < 4; ++e4) {
      const int e = tid + 256 * e4;          // 1024 float4 over 64x64 u tile
      const int kk = e >> 4, s4 = (e & 15) * 4;
      *(float4*)&LB(kk, s4) =
          *(const float4*)(ub + (size_t)(k0 + kk) * D_MODEL + s4);
    }
    __syncthreads();
    const int base = 128 - k0;
    // kt=1: rows <64 have zero contribution (guard zone); wave-uniform skip.
    if (kt == 0 || ry8 >= 64) {
#pragma unroll 4
      for (int g = 0; g < 16; ++g) {
        const int Wg = base + ry8 - 4 * g;     // mult of 4 -> aligned reads
        const float4 w0 = *(const float4*)&lkz[Wg];
        const float4 w1 = *(const float4*)&lkz[Wg + 4];
        const float4 w2 = *(const float4*)&lkz[Wg + 8];
        const float w[12] = {w0.x, w0.y, w0.z, w0.w, w1.x, w1.y, w1.z, w1.w,
                             w2.x, w2.y, w2.z, w2.w};
#pragma unroll
        for (int k2 = 0; k2 < 4; ++k2) {
          const float4 b = *(const float4*)&LB(4 * g + k2, sx4);
          const float bv[4] = {b.x, b.y, b.z, b.w};
#pragma unroll
          for (int ii = 0; ii < 8; ++ii) {
            const float av = w[ii - k2 + 3];   // = KlocZ[base+ry8+ii-(4g+k2)]
#pragma unroll
            for (int jj = 0; jj < 4; ++jj) acc[ii][jj] += av * bv[jj];
          }
        }
      }
    }
    __syncthreads();
  }

  // phase B: Wout * X_c, i split into two 32-i halves (16KB AW panel each)
  const float* xc = gx + ((size_t)c * NSEQ + sgl) * 64;
  for (int ih = 0; ih < 2; ++ih) {
    // AW[i][r] = Wout[ih*32+i][r], 32x128 (1024 float4, 4/thread)
#pragma unroll
    for (int e4 = 0; e4 < 4; ++e4) {
      const int e = tid + 256 * e4;
      const int i_ = e >> 5, r4 = (e & 31) * 4;
      *(float4*)&LAW(i_, r4) =
          *(const float4*)(WoutG + (ih * 32 + i_) * 128 + r4);
    }
    // Bs = X half [32i][64s] from gx[c][s][i] (512 float4, 2/thread);
    // sl-major scalar scatter writes (banks = sl%32, 2-way = free).
#pragma unroll
    for (int e2 = 0; e2 < 2; ++e2) {
      const int e = tid + 256 * e2;
      const int sl = e & 63, i4 = ((e >> 6) & 7) * 4;
      const float4 v = *(const float4*)(xc + (size_t)sl * 64 + ih * 32 + i4);
      LB(i4 + 0, sl) = v.x;
      LB(i4 + 1, sl) = v.y;
      LB(i4 + 2, sl) = v.z;
      LB(i4 + 3, sl) = v.w;
    }
    __syncthreads();
#pragma unroll 8
    for (int kk = 0; kk < 32; ++kk) {
      const float4 a0 = *(const float4*)&LAW(kk, ry8);
      const float4 a1 = *(const float4*)&LAW(kk, ry8 + 4);
      const float4 b = *(const float4*)&LB(kk, sx4);
      const float av[8] = {a0.x, a0.y, a0.z, a0.w, a1.x, a1.y, a1.z, a1.w};
      const float bv[4] = {b.x, b.y, b.z, b.w};
#pragma unroll
      for (int ii = 0; ii < 8; ++ii)
#pragma unroll
        for (int jj = 0; jj < 4; ++jj) acc[ii][jj] += av[ii] * bv[jj];
    }
    __syncthreads();
  }

  // epilogue: rows ry8..ry8+7, cols sx4..sx4+3
  float* ob = out + ((size_t)bi * L_SEQ + c * CH) * D_MODEL + d0;
#pragma unroll
  for (int r = 0; r < 8; ++r) {
    float4 v; v.x = acc[r][0]; v.y = acc[r][1]; v.z = acc[r][2]; v.w = acc[r][3];
    *(float4*)(ob + (size_t)(ry8 + r) * D_MODEL + sx4) = v;
  }
}

extern "C" void kernel_launch(void* const* d_in, const int* in_sizes, int n_in,
                              void* d_out, int out_size, void* d_ws,
                              size_t ws_size, hipStream_t stream) {
  const float* u = (const float*)d_in[0];   // (4, 4096, 512)
  const float* A = (const float*)d_in[1];   // (64, 64)
  const float* B = (const float*)d_in[2];   // (64, 1)
  const float* C = (const float*)d_in[3];   // (1, 64)
  float* out = (float*)d_out;
  float* ws = (float*)d_ws;                 // needs ~16.9 MB
  float* gx = ws + OFF_GX;

  k_prep<<<1, 1024, 0, stream>>>(A, B, C, ws);
  k_proj<<<dim3(32, 32), 256, 0, stream>>>(u, ws, gx);
  k_scan<<<512, 256, 0, stream>>>(ws, gx);
  k_localout<<<dim3(32, 32), 256, 0, stream>>>(u, ws, gx, out);
}